// Round 2
// baseline (4456.316 us; speedup 1.0000x reference)
//
#include <hip/hip_runtime.h>

#define T_STEPS 1000
#define IN 13
#define HID 32
#define ELEMS 2
#define GRPSTEPS 4
#define GRPFLOATS (GRPSTEPS * IN * ELEMS)          // 104 floats per group
#define NGRP (T_STEPS / GRPSTEPS)                  // 250
#define ZROWS 46                                   // 13 x-rows + 32 h-rows + 1 zero pad row
#define ZSLOT (ZROWS * ELEMS)                      // 92 floats per slot

// ---------- f32 activations: fast HW exp + correctly-rounded f32 divide ----------
__device__ __forceinline__ float sigmoid_f(float x) {
    float u = fminf(fmaxf(-x, -60.f), 60.f);
    float e = __expf(u);                    // v_mul_f32 + v_exp_f32
    return 1.0f / (1.0f + e);               // precise f32 div (rcp + NR + fixup)
}
__device__ __forceinline__ float tanh_f(float x) {
    float u = fminf(fmaxf(-2.0f * x, -60.f), 60.f);
    float e = __expf(u);
    return (1.0f - e) / (1.0f + e);
}

// Block = 512 threads = 8 waves, TWO batch elements (ELEMS=2) -> grid 1024 blocks.
// Waves 0-3: layer0; waves 4-7: layer1, pipelined one step behind through LDS.
// Gate rows split across lane pairs (hh = half): per-lane weights <= 32 f32 = 32 VGPRs,
// total budget <= 64 VGPRs -> __launch_bounds__(512, 8) -> 8 waves/SIMD -> 4 blocks/CU
// -> 32 waves/CU (100%), and grid 1024 = exactly 4 blocks x 256 CUs (no tail imbalance).
//
// LDS: zbuf[8 slots][46 rows][2 elems] f32.
//   rows 0..12  = x_t (slot t&7, staged 4-step groups, prefetched ahead)
//   rows 13..44 = h0_{t-1} (L0 at iter k writes h into slot (k+1)&7)
//   row  45     = zero pad (half1's 22-long L0 dot runs a uniform 23-iter loop, w[22]=0)
//
// Per step per lane: 1 dot (23 or 32 f32x2 FMA) -> pair-combine shfl_xor(4) ->
// exactly ONE activation per lane (gate g of elem hh; no duplicated act streams) ->
// xor1/xor2 gather the 4 gates of elem hh -> cell update in F64 (the only long-lived
// accumulator; bounds compounding error) -> tanh(c) in f32 -> g==0 lanes write h.
__global__ __launch_bounds__(512, 8)
void lstm_fused(const float* __restrict__ X,
                const float* __restrict__ Wih0, const float* __restrict__ Whh0,
                const float* __restrict__ bih0, const float* __restrict__ bhh0,
                const float* __restrict__ Wih1, const float* __restrict__ Whh1,
                const float* __restrict__ bih1, const float* __restrict__ bhh1,
                const float* __restrict__ Wc1,  const float* __restrict__ bc1,
                const float* __restrict__ Wc2,  const float* __restrict__ bc2,
                float* __restrict__ out)
{
    const int tid  = threadIdx.x;
    const bool isL1 = (tid >= 256);
    const int L    = tid & 255;                 // layer-local thread
    const int u    = L >> 3;                    // unit 0..31
    const int r    = L & 7;
    const int g    = r & 3;                     // 0=i 1=f 2=g 3=o
    const int hh   = r >> 2;                    // row half AND owned elem (0/1)
    const int row  = (g << 5) + u;              // gate row 0..127
    const int eA   = blockIdx.x * ELEMS;

    __shared__ __align__(16) float zbuf[8][ZROWS][ELEMS];
    __shared__ __align__(16) float h1buf[2][HID][ELEMS];
    __shared__ __align__(16) float hidbuf[HID][ELEMS];

    // ---- per-lane HALF-row of weights (max 32 f32 = 32 VGPRs) ----
    float w[32];
    #pragma unroll
    for (int i = 0; i < 32; ++i) w[i] = 0.f;
    float bias = 0.f;
    if (!isL1) {
        if (hh == 0) {
            #pragma unroll
            for (int i = 0; i < IN; ++i)  w[i]      = Wih0[row*IN + i];
            #pragma unroll
            for (int j = 0; j < 10; ++j)  w[IN + j] = Whh0[row*HID + j];
            bias = bih0[row] + bhh0[row];
        } else {
            #pragma unroll
            for (int j = 0; j < 22; ++j)  w[j] = Whh0[row*HID + 10 + j];
            // w[22] stays 0 -> multiplies the zero pad row
        }
    } else {
        if (hh == 0) {
            #pragma unroll
            for (int j = 0; j < HID; ++j) w[j] = Wih1[row*HID + j];
            bias = bih1[row] + bhh1[row];
        } else {
            #pragma unroll
            for (int j = 0; j < HID; ++j) w[j] = Whh1[row*HID + j];
        }
    }

    // ---- zero h-rows + pad row of all 8 slots; h1[-1] = 0 ----
    for (int i = tid; i < 8 * ZSLOT; i += 512) {
        if ((i % ZSLOT) >= IN * ELEMS) ((float*)zbuf)[i] = 0.f;
    }
    if (tid < 2 * HID) ((float*)h1buf)[tid] = 0.f;      // h1buf[0][*][*]

    // ---- x staging: 52 stagers, float2 each, straight into zbuf x-rows ----
    const bool stager = (tid < GRPFLOATS / 2);          // tid < 52
    int off0 = 0, off1 = 0;
    const float* xg = nullptr;
    float2 xreg = make_float2(0.f, 0.f);
    if (stager) {
        int f0 = tid * 2, f1 = f0 + 1;
        int e0 = f0 / (GRPSTEPS * IN); int r0 = f0 % (GRPSTEPS * IN);
        int t0 = r0 / IN, i0 = r0 % IN;
        int r1 = f1 % (GRPSTEPS * IN);                  // f0 even, span 52 even -> same elem
        int t1 = r1 / IN, i1 = r1 % IN;
        off0 = t0 * ZSLOT + i0 * ELEMS + e0;
        off1 = t1 * ZSLOT + i1 * ELEMS + e0;
        xg = X + (size_t)(eA + e0) * (T_STEPS * IN) + (size_t)r0;
        float2 x0 = *(const float2*)xg;                 // group 0
        ((float*)zbuf)[off0] = x0.x;
        ((float*)zbuf)[off1] = x0.y;
        xreg = *(const float2*)(xg + GRPSTEPS * IN);    // prefetch group 1
    }
    __syncthreads();

    double cd = 0.0;    // F64 cell state of elem hh (duplicated across the 4 g-lanes)

    #pragma unroll 1
    for (int k = 0; k <= T_STEPS; ++k) {
        const int p   = k & 1;
        const int grp = k >> 2;
        const int ph  = k & 3;

        if (ph == 0 && stager) {
            if (grp + 1 < NGRP) {
                const int base = ((grp + 1) & 1) ? 4 * ZSLOT : 0;
                ((float*)zbuf)[base + off0] = xreg.x;
                ((float*)zbuf)[base + off1] = xreg.y;
            }
            if (grp + 2 < NGRP) xreg = *(const float2*)(xg + (size_t)(grp + 2) * GRPSTEPS * IN);
        }

        const bool active = isL1 ? (k >= 1) : (k < T_STEPS);
        if (active) {
            float a0 = bias, a1 = bias;
            if (!isL1) {
                // uniform 23-iter loop; half0 = [x | h0[0..9]], half1 = h0[10..31] + pad
                const float* zp = &zbuf[k & 7][0][0] + (hh ? 23 * ELEMS : 0);
                #pragma unroll
                for (int i = 0; i < 23; ++i) {
                    float2 q = *(const float2*)(zp + i * 2);
                    a0 = fmaf(w[i], q.x, a0);
                    a1 = fmaf(w[i], q.y, a1);
                }
            } else {
                // half0: Wih1 . h0[k-1] (slot k&7 rows 13..44); half1: Whh1 . h1[k-2]
                const float* zp = hh ? &h1buf[p ^ 1][0][0] : &zbuf[k & 7][13][0];
                #pragma unroll
                for (int j = 0; j < HID; ++j) {
                    float2 q = *(const float2*)(zp + j * 2);
                    a0 = fmaf(w[j], q.x, a0);
                    a1 = fmaf(w[j], q.y, a1);
                }
            }

            // pair-combine (commutative add -> halves identical)
            a0 += __shfl_xor(a0, 4);
            a1 += __shfl_xor(a1, 4);

            // ONE activation per lane: gate g of elem hh
            const float xv = hh ? a1 : a0;
            const float v  = (g == 2) ? tanh_f(xv) : sigmoid_f(xv);

            // gather the 4 gates of elem hh across the g-quad
            float t1 = __shfl_xor(v, 1);
            float p0 = (g & 1) ? t1 : v;        // even gate of this pair
            float p1 = (g & 1) ? v  : t1;       // odd gate
            float t2 = __shfl_xor(p0, 2);
            float t3 = __shfl_xor(p1, 2);
            const bool gb = (g & 2);
            float gi = gb ? t2 : p0;
            float gf = gb ? t3 : p1;
            float gg = gb ? p0 : t2;
            float go = gb ? p1 : t3;

            // cell update in f64 (exact products, long-lived accumulator stays precise)
            cd = fma((double)gf, cd, (double)gi * (double)gg);
            float th   = tanh_f((float)cd);
            float hval = go * th;

            if (g == 0) {                       // one writer per (unit, elem)
                if (!isL1) zbuf[(k + 1) & 7][13 + u][hh] = hval;   // pairs with x_{k+1}
                else       h1buf[p][u][hh] = hval;
            }
        }
        __syncthreads();
    }

    // ---- classifier head (f32): hidden = relu(Wc1 @ h1 + bc1); out = Wc2 @ hidden + bc2
    if (tid < 2 * HID) {
        const int e = tid >> 5, j = tid & 31;
        float acc = bc1[j];
        #pragma unroll
        for (int jj = 0; jj < HID; ++jj)
            acc = fmaf(Wc1[j*HID + jj], h1buf[T_STEPS & 1][jj][e], acc);
        hidbuf[j][e] = fmaxf(acc, 0.f);
    }
    __syncthreads();
    if (tid < 3 * ELEMS) {
        const int e = tid / 3, c = tid % 3;
        float vv = bc2[c];
        #pragma unroll
        for (int j = 0; j < HID; ++j)
            vv = fmaf(Wc2[c*HID + j], hidbuf[j][e], vv);
        out[(eA + e) * 3 + c] = vv;
    }
}

extern "C" void kernel_launch(void* const* d_in, const int* in_sizes, int n_in,
                              void* d_out, int out_size, void* d_ws, size_t ws_size,
                              hipStream_t stream) {
    const float* X    = (const float*)d_in[0];
    const float* Wih0 = (const float*)d_in[1];
    const float* Whh0 = (const float*)d_in[2];
    const float* bih0 = (const float*)d_in[3];
    const float* bhh0 = (const float*)d_in[4];
    const float* Wih1 = (const float*)d_in[5];
    const float* Whh1 = (const float*)d_in[6];
    const float* bih1 = (const float*)d_in[7];
    const float* bhh1 = (const float*)d_in[8];
    const float* Wc1  = (const float*)d_in[9];
    const float* bc1  = (const float*)d_in[10];
    const float* Wc2  = (const float*)d_in[11];
    const float* bc2  = (const float*)d_in[12];

    lstm_fused<<<1024, 512, 0, stream>>>(X, Wih0, Whh0, bih0, bhh0,
                                         Wih1, Whh1, bih1, bhh1,
                                         Wc1, bc1, Wc2, bc2, (float*)d_out);
}

// Round 3
// 2929.203 us; speedup vs baseline: 1.5213x; 1.5213x over previous
//
#include <hip/hip_runtime.h>

#define T_STEPS 1000
#define IN 13
#define HID 32
#define ELEMS 2
#define GRPSTEPS 4
#define GRPFLOATS (GRPSTEPS * IN * ELEMS)          // 104 floats per group
#define NGRP (T_STEPS / GRPSTEPS)                  // 250
#define ZROWS 45                                   // 13 x-rows + 32 h-rows
#define ZSLOT (ZROWS * ELEMS)                      // 90 floats per slot

// ---------- f32 activations (identical formulas to R2, which verified absmax=0.0) ----
__device__ __forceinline__ float sigmoid_f(float x) {
    float u = fminf(fmaxf(-x, -60.f), 60.f);
    float e = __expf(u);
    return 1.0f / (1.0f + e);
}
__device__ __forceinline__ float tanh_f(float x) {
    float u = fminf(fmaxf(-2.0f * x, -60.f), 60.f);
    float e = __expf(u);
    return (1.0f - e) / (1.0f + e);
}

// Block = 256 threads = 4 waves, TWO batch elements -> grid 1024 = exactly 4 blocks/CU.
// Waves 0-1: layer0; waves 2-3: layer1 (pipelined one step behind through LDS).
// FULL gate row per lane (no split): per-lane weights 45 (L0) / 64 (L1) f32 VGPRs.
// __launch_bounds__(256,4) -> 128-VGPR budget -> no spill (R2's failure mode), and
// 4 blocks/CU x 4 waves = 4 waves/SIMD (16 waves/CU).
//
// LDS: zbuf[8 slots][45 rows][2 elems] f32.
//   rows 0..12  = x_t (slot t&7, staged in 4-step groups, prefetched 2 groups ahead)
//   rows 13..44 = h0_{t-1} (L0 at iter k writes h0_k into slot (k+1)&7, so slot s
//                           holds the contiguous L0 operand [x_s | h0_{s-1}])
// L0 dot = ONE uniform 45-iter float2 loop over the slot. All lanes of a layer read
// the SAME LDS address each iter -> pure broadcast, conflict-free.
//
// Per step per lane: dot (2 accs = elems 0,1) -> 2 activations (gate g, both elems)
// -> xor1/xor2 quad transpose gathers the 4 gates of elem (g&1) -> cell update in
// f64 (only long-lived accumulator) -> tanh(c) -> lanes g<2 write h (one writer per
// (unit, elem)).
__global__ __launch_bounds__(256, 4)
void lstm_fused(const float* __restrict__ X,
                const float* __restrict__ Wih0, const float* __restrict__ Whh0,
                const float* __restrict__ bih0, const float* __restrict__ bhh0,
                const float* __restrict__ Wih1, const float* __restrict__ Whh1,
                const float* __restrict__ bih1, const float* __restrict__ bhh1,
                const float* __restrict__ Wc1,  const float* __restrict__ bc1,
                const float* __restrict__ Wc2,  const float* __restrict__ bc2,
                float* __restrict__ out)
{
    const int tid  = threadIdx.x;
    const bool isL1 = (tid >= 128);
    const int L    = tid & 127;                 // layer-local thread
    const int u    = L >> 2;                    // unit 0..31
    const int g    = L & 3;                     // 0=i 1=f 2=g 3=o
    const int row  = (g << 5) + u;              // gate row 0..127
    const int eA   = blockIdx.x * ELEMS;

    __shared__ __align__(16) float zbuf[8][ZROWS][ELEMS];
    __shared__ __align__(16) float h1buf[2][HID][ELEMS];
    __shared__ __align__(16) float hidbuf[HID][ELEMS];

    // ---- per-lane FULL row of weights ----
    float w[64];
    float bias;
    if (!isL1) {
        #pragma unroll
        for (int i = 0; i < IN; ++i)  w[i]      = Wih0[row*IN + i];
        #pragma unroll
        for (int j = 0; j < HID; ++j) w[IN + j] = Whh0[row*HID + j];
        #pragma unroll
        for (int j = IN + HID; j < 64; ++j) w[j] = 0.f;
        bias = bih0[row] + bhh0[row];
    } else {
        #pragma unroll
        for (int j = 0; j < HID; ++j) w[j]       = Wih1[row*HID + j];
        #pragma unroll
        for (int j = 0; j < HID; ++j) w[HID + j] = Whh1[row*HID + j];
        bias = bih1[row] + bhh1[row];
    }

    // ---- zero h-rows of all 8 slots; h1[-1] = 0 ----
    for (int i = tid; i < 8 * ZSLOT; i += 256) {
        if ((i % ZSLOT) >= IN * ELEMS) ((float*)zbuf)[i] = 0.f;
    }
    if (tid < 2 * HID) ((float*)h1buf)[tid] = 0.f;      // h1buf[0][*][*]

    // ---- x staging: 52 stagers (wave 0), float2 each, straight into zbuf x-rows ----
    const bool stager = (tid < GRPFLOATS / 2);          // tid < 52
    int off0 = 0, off1 = 0;
    const float* xg = nullptr;
    float2 xreg = make_float2(0.f, 0.f);
    if (stager) {
        int f0 = tid * 2, f1 = f0 + 1;
        int e0 = f0 / (GRPSTEPS * IN); int r0 = f0 % (GRPSTEPS * IN);
        int t0 = r0 / IN, i0 = r0 % IN;
        int r1 = f1 % (GRPSTEPS * IN);                  // f0 even, span 52 even -> same elem
        int t1 = r1 / IN, i1 = r1 % IN;
        off0 = t0 * ZSLOT + i0 * ELEMS + e0;
        off1 = t1 * ZSLOT + i1 * ELEMS + e0;
        xg = X + (size_t)(eA + e0) * (T_STEPS * IN) + (size_t)r0;
        float2 x0 = *(const float2*)xg;                 // group 0
        ((float*)zbuf)[off0] = x0.x;
        ((float*)zbuf)[off1] = x0.y;
        xreg = *(const float2*)(xg + GRPSTEPS * IN);    // prefetch group 1
    }
    __syncthreads();

    double cd = 0.0;    // f64 cell state of elem (g&1), duplicated across the g-pair

    #pragma unroll 1
    for (int k = 0; k <= T_STEPS; ++k) {
        const int p   = k & 1;
        const int grp = k >> 2;
        const int ph  = k & 3;

        if (ph == 0 && stager) {
            if (grp + 1 < NGRP) {
                const int base = ((grp + 1) & 1) ? 4 * ZSLOT : 0;
                ((float*)zbuf)[base + off0] = xreg.x;
                ((float*)zbuf)[base + off1] = xreg.y;
            }
            if (grp + 2 < NGRP) xreg = *(const float2*)(xg + (size_t)(grp + 2) * GRPSTEPS * IN);
        }

        const bool active = isL1 ? (k >= 1) : (k < T_STEPS);
        if (active) {
            float a0 = bias, a1 = bias;
            if (!isL1) {
                // one uniform 45-iter loop over [x_k | h0_{k-1}] (broadcast reads)
                const float* zp = &zbuf[k & 7][0][0];
                #pragma unroll
                for (int i = 0; i < 45; ++i) {
                    float2 q = *(const float2*)(zp + i * 2);
                    a0 = fmaf(w[i], q.x, a0);
                    a1 = fmaf(w[i], q.y, a1);
                }
            } else {
                // Wih1 . h0_{k-1} (slot k&7 rows 13..44) then Whh1 . h1_{k-2}
                const float* zp = &zbuf[k & 7][13][0];
                #pragma unroll
                for (int j = 0; j < HID; ++j) {
                    float2 q = *(const float2*)(zp + j * 2);
                    a0 = fmaf(w[j], q.x, a0);
                    a1 = fmaf(w[j], q.y, a1);
                }
                const float* hq = &h1buf[p ^ 1][0][0];
                #pragma unroll
                for (int j = 0; j < HID; ++j) {
                    float2 q = *(const float2*)(hq + j * 2);
                    a0 = fmaf(w[HID + j], q.x, a0);
                    a1 = fmaf(w[HID + j], q.y, a1);
                }
            }

            // 2 activations per lane: gate g of elems 0,1
            const bool istanh = (g == 2);
            float v0 = istanh ? tanh_f(a0) : sigmoid_f(a0);
            float v1 = istanh ? tanh_f(a1) : sigmoid_f(a1);

            // quad transpose: lane ends with all 4 gates of elem e = g&1
            float t0 = __shfl_xor(v0, 1);       // act(g^1, e0)
            float t1 = __shfl_xor(v1, 1);       // act(g^1, e1)
            const bool odd = (g & 1);
            float pe = odd ? t1 : v0;           // even gate of pair {g,g^1}, elem e
            float po = odd ? v1 : t0;           // odd  gate of pair, elem e
            float t2 = __shfl_xor(pe, 2);
            float t3 = __shfl_xor(po, 2);
            const bool gb = (g & 2);
            float gi = gb ? t2 : pe;
            float gf = gb ? t3 : po;
            float gg = gb ? pe : t2;
            float go = gb ? po : t3;

            // cell update in f64 (exact products; bounds compounding error)
            cd = fma((double)gf, cd, (double)gi * (double)gg);
            float th   = tanh_f((float)cd);
            float hval = go * th;

            if (g < 2) {                        // one writer per (unit, elem=g)
                if (!isL1) zbuf[(k + 1) & 7][13 + u][g] = hval;   // pairs with x_{k+1}
                else       h1buf[p][u][g] = hval;
            }
        }
        __syncthreads();
    }

    // ---- classifier head (f32): hidden = relu(Wc1 @ h1 + bc1); out = Wc2 @ hidden + bc2
    if (tid < 2 * HID) {
        const int e = tid >> 5, j = tid & 31;
        float acc = bc1[j];
        #pragma unroll
        for (int jj = 0; jj < HID; ++jj)
            acc = fmaf(Wc1[j*HID + jj], h1buf[T_STEPS & 1][jj][e], acc);
        hidbuf[j][e] = fmaxf(acc, 0.f);
    }
    __syncthreads();
    if (tid < 3 * ELEMS) {
        const int e = tid / 3, c = tid % 3;
        float vv = bc2[c];
        #pragma unroll
        for (int j = 0; j < HID; ++j)
            vv = fmaf(Wc2[c*HID + j], hidbuf[j][e], vv);
        out[(eA + e) * 3 + c] = vv;
    }
}

extern "C" void kernel_launch(void* const* d_in, const int* in_sizes, int n_in,
                              void* d_out, int out_size, void* d_ws, size_t ws_size,
                              hipStream_t stream) {
    const float* X    = (const float*)d_in[0];
    const float* Wih0 = (const float*)d_in[1];
    const float* Whh0 = (const float*)d_in[2];
    const float* bih0 = (const float*)d_in[3];
    const float* bhh0 = (const float*)d_in[4];
    const float* Wih1 = (const float*)d_in[5];
    const float* Whh1 = (const float*)d_in[6];
    const float* bih1 = (const float*)d_in[7];
    const float* bhh1 = (const float*)d_in[8];
    const float* Wc1  = (const float*)d_in[9];
    const float* bc1  = (const float*)d_in[10];
    const float* Wc2  = (const float*)d_in[11];
    const float* bc2  = (const float*)d_in[12];

    lstm_fused<<<1024, 256, 0, stream>>>(X, Wih0, Whh0, bih0, bhh0,
                                         Wih1, Whh1, bih1, bhh1,
                                         Wc1, bc1, Wc2, bc2, (float*)d_out);
}

// Round 4
// 2185.660 us; speedup vs baseline: 2.0389x; 1.3402x over previous
//
#include <hip/hip_runtime.h>

#define T_STEPS 1000
#define IN 13
#define HID 32
#define ELEMS 2
#define GRPSTEPS 4
#define GRPFLOATS (GRPSTEPS * IN * ELEMS)   // 104 floats per x-group
#define NGRP (T_STEPS / GRPSTEPS)           // 250
#define ZROWS 48                            // 32 h-rows + 13 x-rows + 3 zero pad
#define ZSLOT (ZROWS * ELEMS)               // 96 floats per slot
#define ZTOT  (8 * ZSLOT)                   // 768
#define H1OFF (ZTOT + 8)                    // +8 floats pad -> h1 starts at bank 8
#define HIDOFF (H1OFF + 2 * HID * ELEMS)    // 904
#define SMEMF  (HIDOFF + HID * ELEMS)       // 968 floats

// ---------- f32 activations (identical formulas to R2/R3, harness-verified) ----------
__device__ __forceinline__ float sigmoid_f(float x) {
    float u = fminf(fmaxf(-x, -60.f), 60.f);
    float e = __expf(u);
    return 1.0f / (1.0f + e);
}
__device__ __forceinline__ float tanh_f(float x) {
    float u = fminf(fmaxf(-2.0f * x, -60.f), 60.f);
    float e = __expf(u);
    return (1.0f - e) / (1.0f + e);
}

// Block = 512 thr = 8 waves, ELEMS=2 -> grid 1024. Waves 0-3: L0; waves 4-7: L1
// (pipelined one step behind). Within a layer: unit u = L>>3 (32 units over 4 waves),
// r = L&7 = K-CHUNK index. Lane r holds, for ALL 4 GATES of its unit, the weights of
// K-chunk r: 4x6=24 f32 (L0, K=45 padded to 48) / 4x8=32 f32 (L1, K=64).
//   -> per-lane regs ~70 <= 128 budget, weights live in ARCH VGPRs (R3's AGPR tax gone)
//   -> per-lane operand = only its chunk: 3-4 x ds_read_b128 per step (R3: 45-64 ds ops)
// Partial dots A[e][q] are butterfly-reduced over r (shfl_xor 4,2,1; no LDS): lane r
// ends with the full preact of (gate q=r&3, elem e=r>>2) -> ONE activation per lane ->
// quad gather (xor 1,2) -> f64 cell update -> (r&3)==0 writes h.
//
// LDS operand order is [h(32) | x(13) | pad(3)] so every chunk read is 16B-aligned;
// weights are loaded in the matching permuted order (sum reordering only).
__global__ __launch_bounds__(512, 4)
void lstm_fused(const float* __restrict__ X,
                const float* __restrict__ Wih0, const float* __restrict__ Whh0,
                const float* __restrict__ bih0, const float* __restrict__ bhh0,
                const float* __restrict__ Wih1, const float* __restrict__ Whh1,
                const float* __restrict__ bih1, const float* __restrict__ bhh1,
                const float* __restrict__ Wc1,  const float* __restrict__ bc1,
                const float* __restrict__ Wc2,  const float* __restrict__ bc2,
                float* __restrict__ out)
{
    const int tid  = threadIdx.x;
    const bool isL1 = (tid >= 256);
    const int L    = tid & 255;             // layer-local thread
    const int u    = L >> 3;                // unit 0..31
    const int r    = L & 7;                 // K-chunk index
    const int q0   = r & 3;                 // final gate owned after reduction
    const int e0f  = r >> 2;                // final elem owned after reduction
    const int eA   = blockIdx.x * ELEMS;

    __shared__ __align__(16) float smem[SMEMF];

    // ---- weights: 4 gates x chunk r (combined operand order = [Whh | Wih | 0]) ----
    float w[32];
    float bias;
    if (!isL1) {
        #pragma unroll
        for (int q = 0; q < 4; ++q) {
            const int row = (q << 5) | u;
            #pragma unroll
            for (int cc = 0; cc < 6; ++cc) {
                const int j = 6 * r + cc;
                float v;
                if (j < HID)          v = Whh0[row * HID + j];
                else if (j < HID+IN)  v = Wih0[row * IN + (j - HID)];
                else                  v = 0.f;
                w[q * 6 + cc] = v;
            }
        }
        const int rowf = (q0 << 5) | u;
        bias = bih0[rowf] + bhh0[rowf];
    } else {
        #pragma unroll
        for (int q = 0; q < 4; ++q) {
            const int row = (q << 5) | u;
            #pragma unroll
            for (int cc = 0; cc < 8; ++cc) {
                const int j = 8 * r + cc;               // [h0(32) | h1(32)]
                w[q * 8 + cc] = (j < HID) ? Wih1[row * HID + j]
                                          : Whh1[row * HID + (j - HID)];
            }
        }
        const int rowf = (q0 << 5) | u;
        bias = bih1[rowf] + bhh1[rowf];
    }

    // ---- zero zbuf (h-rows + pads; x-rows get overwritten) and h1[-1] ----
    for (int i = tid; i < ZTOT; i += 512) smem[i] = 0.f;
    if (tid < HID * ELEMS) smem[H1OFF + tid] = 0.f;     // h1 parity 0

    // ---- x staging: 52 stagers, float2 each, into x-rows (HID+i) of the slots ----
    const bool stager = (tid < GRPFLOATS / 2);          // tid < 52
    int off0 = 0, off1 = 0;
    const float* xg = nullptr;
    float2 xreg = make_float2(0.f, 0.f);
    if (stager) {
        int f0 = tid * 2, f1 = f0 + 1;
        int e0 = f0 / (GRPSTEPS * IN); int r0 = f0 % (GRPSTEPS * IN);
        int t0 = r0 / IN, i0 = r0 % IN;
        int r1 = f1 % (GRPSTEPS * IN);                  // f0 even, span 52 even -> same elem
        int t1 = r1 / IN, i1 = r1 % IN;
        off0 = t0 * ZSLOT + (HID + i0) * ELEMS + e0;
        off1 = t1 * ZSLOT + (HID + i1) * ELEMS + e0;
        xg = X + (size_t)(eA + e0) * (T_STEPS * IN) + (size_t)r0;
        float2 x0 = *(const float2*)xg;                 // group 0
        smem[off0] = x0.x;
        smem[off1] = x0.y;
        xreg = *(const float2*)(xg + GRPSTEPS * IN);    // prefetch group 1
    }
    __syncthreads();

    double cd = 0.0;    // f64 cell state of (u, e0f), duplicated across the gate quad

    #pragma unroll 1
    for (int k = 0; k <= T_STEPS; ++k) {
        const int p   = k & 1;
        const int grp = k >> 2;
        const int ph  = k & 3;

        if (ph == 0 && stager) {
            if (grp + 1 < NGRP) {
                const int base = ((grp + 1) & 1) ? 4 * ZSLOT : 0;
                smem[base + off0] = xreg.x;
                smem[base + off1] = xreg.y;
            }
            if (grp + 2 < NGRP) xreg = *(const float2*)(xg + (size_t)(grp + 2) * GRPSTEPS * IN);
        }

        const bool active = isL1 ? (k >= 1) : (k < T_STEPS);
        if (active) {
            float A[8];                                  // A[e*4+q], partial over chunk r
            #pragma unroll
            for (int i = 0; i < 8; ++i) A[i] = 0.f;

            if (!isL1) {
                const float* zp = smem + (k & 7) * ZSLOT + r * 12;   // 6 rows x 2 elems
                float4 z0 = *(const float4*)(zp);
                float4 z1 = *(const float4*)(zp + 4);
                float4 z2 = *(const float4*)(zp + 8);
                float ze0[6] = {z0.x, z0.z, z1.x, z1.z, z2.x, z2.z};
                float ze1[6] = {z0.y, z0.w, z1.y, z1.w, z2.y, z2.w};
                #pragma unroll
                for (int q = 0; q < 4; ++q)
                    #pragma unroll
                    for (int cc = 0; cc < 6; ++cc) {
                        A[q]     = fmaf(w[q*6+cc], ze0[cc], A[q]);
                        A[4+q]   = fmaf(w[q*6+cc], ze1[cc], A[4+q]);
                    }
            } else {
                const float* zp = (r < 4)
                    ? (smem + (k & 7) * ZSLOT + r * 16)                       // h0_{k-1}
                    : (smem + H1OFF + ((p ^ 1) * HID * ELEMS) + (r - 4) * 16);// h1_{k-2}
                float4 z0 = *(const float4*)(zp);
                float4 z1 = *(const float4*)(zp + 4);
                float4 z2 = *(const float4*)(zp + 8);
                float4 z3 = *(const float4*)(zp + 12);
                float ze0[8] = {z0.x, z0.z, z1.x, z1.z, z2.x, z2.z, z3.x, z3.z};
                float ze1[8] = {z0.y, z0.w, z1.y, z1.w, z2.y, z2.w, z3.y, z3.w};
                #pragma unroll
                for (int q = 0; q < 4; ++q)
                    #pragma unroll
                    for (int cc = 0; cc < 8; ++cc) {
                        A[q]     = fmaf(w[q*8+cc], ze0[cc], A[q]);
                        A[4+q]   = fmaf(w[q*8+cc], ze1[cc], A[4+q]);
                    }
            }

            // ---- 3-level butterfly over r: lane r ends with full preact of (q0, e0f)
            const bool hi4 = (r & 4), hi2 = (r & 2), hi1 = (r & 1);
            float B0, B1, B2, B3, C0, C1, S;
            {   // M=4: keep own elem half, exchange the other
                float s0 = hi4 ? A[0] : A[4], k0 = hi4 ? A[4] : A[0];
                float s1 = hi4 ? A[1] : A[5], k1 = hi4 ? A[5] : A[1];
                float s2 = hi4 ? A[2] : A[6], k2 = hi4 ? A[6] : A[2];
                float s3 = hi4 ? A[3] : A[7], k3 = hi4 ? A[7] : A[3];
                B0 = k0 + __shfl_xor(s0, 4);
                B1 = k1 + __shfl_xor(s1, 4);
                B2 = k2 + __shfl_xor(s2, 4);
                B3 = k3 + __shfl_xor(s3, 4);
            }
            {   // M=2: keep gates with (q&2)==(r&2)
                float s0 = hi2 ? B0 : B2, k0 = hi2 ? B2 : B0;
                float s1 = hi2 ? B1 : B3, k1 = hi2 ? B3 : B1;
                C0 = k0 + __shfl_xor(s0, 2);
                C1 = k1 + __shfl_xor(s1, 2);
            }
            {   // M=1
                float s = hi1 ? C0 : C1, kk = hi1 ? C1 : C0;
                S = kk + __shfl_xor(s, 1);
            }
            S += bias;

            // ---- ONE activation per lane: gate q0 of elem e0f ----
            float v = (q0 == 2) ? tanh_f(S) : sigmoid_f(S);

            // ---- quad gather (within the 4-lane e-group): all gates of (u, e0f) ----
            float t1 = __shfl_xor(v, 1);
            float pe = (q0 & 1) ? t1 : v;
            float po = (q0 & 1) ? v  : t1;
            float t2 = __shfl_xor(pe, 2);
            float t3 = __shfl_xor(po, 2);
            const bool gb = (q0 & 2);
            float gi = gb ? t2 : pe;
            float gf = gb ? t3 : po;
            float gg = gb ? pe : t2;
            float go = gb ? po : t3;

            // ---- f64 cell update (long-lived accumulator stays exact) ----
            cd = fma((double)gf, cd, (double)gi * (double)gg);
            float th   = tanh_f((float)cd);
            float hval = go * th;

            if (q0 == 0) {                  // one writer per (unit, elem)
                if (!isL1) smem[((k + 1) & 7) * ZSLOT + u * ELEMS + e0f] = hval;
                else       smem[H1OFF + p * HID * ELEMS + u * ELEMS + e0f] = hval;
            }
        }
        __syncthreads();
    }

    // ---- classifier head (f32): hidden = relu(Wc1 @ h1 + bc1); out = Wc2 @ hidden + bc2
    // final h1 is parity (T_STEPS & 1) = 0
    if (tid < ELEMS * HID) {
        const int e = tid >> 5, j = tid & 31;
        float acc = bc1[j];
        #pragma unroll
        for (int jj = 0; jj < HID; ++jj)
            acc = fmaf(Wc1[j*HID + jj], smem[H1OFF + jj * ELEMS + e], acc);
        smem[HIDOFF + j * ELEMS + e] = fmaxf(acc, 0.f);
    }
    __syncthreads();
    if (tid < 3 * ELEMS) {
        const int e = tid / 3, c = tid % 3;
        float vv = bc2[c];
        #pragma unroll
        for (int j = 0; j < HID; ++j)
            vv = fmaf(Wc2[c*HID + j], smem[HIDOFF + j * ELEMS + e], vv);
        out[(eA + e) * 3 + c] = vv;
    }
}

extern "C" void kernel_launch(void* const* d_in, const int* in_sizes, int n_in,
                              void* d_out, int out_size, void* d_ws, size_t ws_size,
                              hipStream_t stream) {
    const float* X    = (const float*)d_in[0];
    const float* Wih0 = (const float*)d_in[1];
    const float* Whh0 = (const float*)d_in[2];
    const float* bih0 = (const float*)d_in[3];
    const float* bhh0 = (const float*)d_in[4];
    const float* Wih1 = (const float*)d_in[5];
    const float* Whh1 = (const float*)d_in[6];
    const float* bih1 = (const float*)d_in[7];
    const float* bhh1 = (const float*)d_in[8];
    const float* Wc1  = (const float*)d_in[9];
    const float* bc1  = (const float*)d_in[10];
    const float* Wc2  = (const float*)d_in[11];
    const float* bc2  = (const float*)d_in[12];

    lstm_fused<<<1024, 512, 0, stream>>>(X, Wih0, Whh0, bih0, bhh0,
                                         Wih1, Whh1, bih1, bhh1,
                                         Wc1, bc1, Wc2, bc2, (float*)d_out);
}

// Round 5
// 1621.631 us; speedup vs baseline: 2.7480x; 1.3478x over previous
//
#include <hip/hip_runtime.h>

#define T_STEPS 1000
#define IN 13
#define HID 32
#define ELEMS 2
#define GRPSTEPS 4
#define GRPFLOATS (GRPSTEPS * IN * ELEMS)   // 104 floats per x-group
#define NGRP (T_STEPS / GRPSTEPS)           // 250
#define ZROWS 48                            // 32 h-rows + 13 x-rows + 3 zero pad
#define ZSLOT (ZROWS * ELEMS)               // 96 floats per slot
#define ZTOT  (8 * ZSLOT)                   // 768
#define H1OFF (ZTOT + 8)                    // h1 double buffer
#define HIDOFF (H1OFF + 2 * HID * ELEMS)    // 904
#define SMEMF  (HIDOFF + HID * ELEMS)       // 968 floats

// ---- cross-lane primitives: DPP quad_perm (VALU pipe, no LDS) + ds_swizzle imm ----
#define DPP_XOR1 0xB1   // quad perm [1,0,3,2]
#define DPP_XOR2 0x4E   // quad perm [2,3,0,1]
#define DPP_XOR3 0x1B   // quad perm [3,2,1,0]
template<int CTRL>
__device__ __forceinline__ float dpp_qp(float x) {
    return __int_as_float(__builtin_amdgcn_update_dpp(
        0, __float_as_int(x), CTRL, 0xF, 0xF, true));
}
__device__ __forceinline__ float swz_xor4(float x) {   // xor lane^4 within 32 (imm pattern)
    return __int_as_float(__builtin_amdgcn_ds_swizzle(__float_as_int(x), 0x101F));
}

// Structure = R4 (8-lane K-chunk groups, dual-elem FMA core, 1 barrier/step), with:
//  * weights/bias PRE-SCALED by -log2e (sigmoid gates) / -2log2e (g gate): activations
//    run in exp2 domain: act = fma(actA, rcp(1+exp2(S)), actB) -- no clamps, no NR.
//  * butterfly xor2/xor1 + cell-path shuffles = DPP quad_perm (1 instr, ~2cy);
//    only the xor4 level uses ds_swizzle (immediate pattern, no addr calc).
//  * asymmetric cell update: lane q0==0 of each quad assembles gf / gi*gg / go via
//    3 DPPs; cd is valid ONLY on that lane (others carry garbage, never read).
//  * f32 cell state (f-gate ~0.5 contracts per-step rounding; validated tolerance).
__global__ __launch_bounds__(512, 4)
void lstm_fused(const float* __restrict__ X,
                const float* __restrict__ Wih0, const float* __restrict__ Whh0,
                const float* __restrict__ bih0, const float* __restrict__ bhh0,
                const float* __restrict__ Wih1, const float* __restrict__ Whh1,
                const float* __restrict__ bih1, const float* __restrict__ bhh1,
                const float* __restrict__ Wc1,  const float* __restrict__ bc1,
                const float* __restrict__ Wc2,  const float* __restrict__ bc2,
                float* __restrict__ out)
{
    const int tid  = threadIdx.x;
    const bool isL1 = (tid >= 256);
    const int L    = tid & 255;             // layer-local thread
    const int u    = L >> 3;                // unit 0..31
    const int r    = L & 7;                 // K-chunk index
    const int q0   = r & 3;                 // gate owned after reduction
    const int e0f  = r >> 2;                // elem owned after reduction
    const int eA   = blockIdx.x * ELEMS;

    __shared__ __align__(16) float smem[SMEMF];

    const float SCL = -1.44269504088896340736f;         // -log2(e)
    // per-gate preactivation scale: sigmoid gates -log2e, tanh gate -2log2e
    const float sgate[4] = {SCL, SCL, 2.f * SCL, SCL};

    // ---- weights: 4 gates x chunk r, PRE-SCALED (operand order = [Whh | Wih | 0]) ----
    float w[32];
    float bias;
    if (!isL1) {
        #pragma unroll
        for (int q = 0; q < 4; ++q) {
            const int row = (q << 5) | u;
            #pragma unroll
            for (int cc = 0; cc < 6; ++cc) {
                const int j = 6 * r + cc;
                float v;
                if (j < HID)          v = Whh0[row * HID + j];
                else if (j < HID+IN)  v = Wih0[row * IN + (j - HID)];
                else                  v = 0.f;
                w[q * 6 + cc] = sgate[q] * v;
            }
        }
        const int rowf = (q0 << 5) | u;
        bias = sgate[q0] * (bih0[rowf] + bhh0[rowf]);
    } else {
        #pragma unroll
        for (int q = 0; q < 4; ++q) {
            const int row = (q << 5) | u;
            #pragma unroll
            for (int cc = 0; cc < 8; ++cc) {
                const int j = 8 * r + cc;               // [h0(32) | h1(32)]
                float v = (j < HID) ? Wih1[row * HID + j]
                                    : Whh1[row * HID + (j - HID)];
                w[q * 8 + cc] = sgate[q] * v;
            }
        }
        const int rowf = (q0 << 5) | u;
        bias = sgate[q0] * (bih1[rowf] + bhh1[rowf]);
    }
    // per-lane activation constants: v = fma(actA, rcp(1+exp2(S)), actB)
    const float actA = (q0 == 2) ? 2.f : 1.f;
    const float actB = (q0 == 2) ? -1.f : 0.f;
    const float C2   = 2.f * SCL;                        // tanh(c) input scale

    // ---- zero zbuf (h-rows + pads) and h1[-1] ----
    for (int i = tid; i < ZTOT; i += 512) smem[i] = 0.f;
    if (tid < HID * ELEMS) smem[H1OFF + tid] = 0.f;     // h1 parity 0

    // ---- x staging: 52 stagers, float2 each, into x-rows (HID+i) of the slots ----
    const bool stager = (tid < GRPFLOATS / 2);          // tid < 52
    int off0 = 0, off1 = 0;
    const float* xg = nullptr;
    float2 xreg = make_float2(0.f, 0.f);
    if (stager) {
        int f0 = tid * 2, f1 = f0 + 1;
        int e0 = f0 / (GRPSTEPS * IN); int r0 = f0 % (GRPSTEPS * IN);
        int t0 = r0 / IN, i0 = r0 % IN;
        int r1 = f1 % (GRPSTEPS * IN);                  // f0 even, span 52 even -> same elem
        int t1 = r1 / IN, i1 = r1 % IN;
        off0 = t0 * ZSLOT + (HID + i0) * ELEMS + e0;
        off1 = t1 * ZSLOT + (HID + i1) * ELEMS + e0;
        xg = X + (size_t)(eA + e0) * (T_STEPS * IN) + (size_t)r0;
        float2 x0 = *(const float2*)xg;                 // group 0
        smem[off0] = x0.x;
        smem[off1] = x0.y;
        xreg = *(const float2*)(xg + GRPSTEPS * IN);    // prefetch group 1
    }
    __syncthreads();

    float cd = 0.f;     // f32 cell state; VALID ONLY on lanes with q0==0

    #pragma unroll 1
    for (int k = 0; k <= T_STEPS; ++k) {
        const int p   = k & 1;
        const int grp = k >> 2;
        const int ph  = k & 3;

        if (ph == 0 && stager) {
            if (grp + 1 < NGRP) {
                const int base = ((grp + 1) & 1) ? 4 * ZSLOT : 0;
                smem[base + off0] = xreg.x;
                smem[base + off1] = xreg.y;
            }
            if (grp + 2 < NGRP) xreg = *(const float2*)(xg + (size_t)(grp + 2) * GRPSTEPS * IN);
        }

        const bool active = isL1 ? (k >= 1) : (k < T_STEPS);
        if (active) {
            float A[8];                                  // A[e*4+q], partial over chunk r
            #pragma unroll
            for (int i = 0; i < 8; ++i) A[i] = 0.f;

            if (!isL1) {
                const float* zp = smem + (k & 7) * ZSLOT + r * 12;   // 6 rows x 2 elems
                float4 z0 = *(const float4*)(zp);
                float4 z1 = *(const float4*)(zp + 4);
                float ze0a[4] = {z0.x, z0.z, z1.x, z1.z};
                float ze1a[4] = {z0.y, z0.w, z1.y, z1.w};
                #pragma unroll
                for (int q = 0; q < 4; ++q)
                    #pragma unroll
                    for (int cc = 0; cc < 4; ++cc) {
                        A[q]   = fmaf(w[q*6+cc], ze0a[cc], A[q]);
                        A[4+q] = fmaf(w[q*6+cc], ze1a[cc], A[4+q]);
                    }
                float4 z2 = *(const float4*)(zp + 8);
                float ze0b[2] = {z2.x, z2.z};
                float ze1b[2] = {z2.y, z2.w};
                #pragma unroll
                for (int q = 0; q < 4; ++q)
                    #pragma unroll
                    for (int cc = 0; cc < 2; ++cc) {
                        A[q]   = fmaf(w[q*6+4+cc], ze0b[cc], A[q]);
                        A[4+q] = fmaf(w[q*6+4+cc], ze1b[cc], A[4+q]);
                    }
            } else {
                const float* zp = (r < 4)
                    ? (smem + (k & 7) * ZSLOT + r * 16)                       // h0_{k-1}
                    : (smem + H1OFF + ((p ^ 1) * HID * ELEMS) + (r - 4) * 16);// h1_{k-2}
                float4 z0 = *(const float4*)(zp);
                float4 z1 = *(const float4*)(zp + 4);
                float ze0a[4] = {z0.x, z0.z, z1.x, z1.z};
                float ze1a[4] = {z0.y, z0.w, z1.y, z1.w};
                #pragma unroll
                for (int q = 0; q < 4; ++q)
                    #pragma unroll
                    for (int cc = 0; cc < 4; ++cc) {
                        A[q]   = fmaf(w[q*8+cc], ze0a[cc], A[q]);
                        A[4+q] = fmaf(w[q*8+cc], ze1a[cc], A[4+q]);
                    }
                float4 z2 = *(const float4*)(zp + 8);
                float4 z3 = *(const float4*)(zp + 12);
                float ze0b[4] = {z2.x, z2.z, z3.x, z3.z};
                float ze1b[4] = {z2.y, z2.w, z3.y, z3.w};
                #pragma unroll
                for (int q = 0; q < 4; ++q)
                    #pragma unroll
                    for (int cc = 0; cc < 4; ++cc) {
                        A[q]   = fmaf(w[q*8+4+cc], ze0b[cc], A[q]);
                        A[4+q] = fmaf(w[q*8+4+cc], ze1b[cc], A[4+q]);
                    }
            }

            // ---- reduction over r: xor4 via ds_swizzle, xor2/xor1 via DPP quad_perm
            const bool hi4 = (r & 4), hi2 = (r & 2), hi1 = (r & 1);
            float S;
            {
                float s0 = hi4 ? A[0] : A[4], k0 = hi4 ? A[4] : A[0];
                float s1 = hi4 ? A[1] : A[5], k1 = hi4 ? A[5] : A[1];
                float s2 = hi4 ? A[2] : A[6], k2 = hi4 ? A[6] : A[2];
                float s3 = hi4 ? A[3] : A[7], k3 = hi4 ? A[7] : A[3];
                float B0 = k0 + swz_xor4(s0);
                float B1 = k1 + swz_xor4(s1);
                float B2 = k2 + swz_xor4(s2);
                float B3 = k3 + swz_xor4(s3);
                float s4 = hi2 ? B0 : B2, k4 = hi2 ? B2 : B0;
                float s5 = hi2 ? B1 : B3, k5 = hi2 ? B3 : B1;
                float C0 = k4 + dpp_qp<DPP_XOR2>(s4);
                float C1 = k5 + dpp_qp<DPP_XOR2>(s5);
                float s6 = hi1 ? C0 : C1, k6 = hi1 ? C1 : C0;
                S = k6 + dpp_qp<DPP_XOR1>(s6);
            }
            S += bias;

            // ---- activation in exp2 domain: v = fma(actA, rcp(1+exp2(S)), actB) ----
            float e2 = exp2f(S);
            float rr = __builtin_amdgcn_rcpf(1.0f + e2);
            float v  = fmaf(actA, rr, actB);    // lane q0: gate q0 of elem e0f

            // ---- asymmetric cell update (valid on lanes q0==0) ----
            float gg2  = dpp_qp<DPP_XOR2>(v);   // lane0 <- gg
            float prod = v * gg2;               // lane0: gi*gg (lane2 computes same)
            float gf1  = dpp_qp<DPP_XOR1>(v);   // lane0 <- gf
            cd = fmaf(gf1, cd, prod);           // valid on q0==0 only
            float e2c = exp2f(cd * C2);
            float th  = fmaf(2.0f, __builtin_amdgcn_rcpf(1.0f + e2c), -1.0f); // tanh(c)
            float go3 = dpp_qp<DPP_XOR3>(v);    // lane0 <- go
            float hval = th * go3;

            if (q0 == 0) {                      // one writer per (unit, elem)
                if (!isL1) smem[((k + 1) & 7) * ZSLOT + u * ELEMS + e0f] = hval;
                else       smem[H1OFF + p * HID * ELEMS + u * ELEMS + e0f] = hval;
            }
        }
        __syncthreads();
    }

    // ---- classifier head (f32): hidden = relu(Wc1 @ h1 + bc1); out = Wc2 @ hidden + bc2
    // final h1 parity = (T_STEPS & 1) = 0
    if (tid < ELEMS * HID) {
        const int e = tid >> 5, j = tid & 31;
        float acc = bc1[j];
        #pragma unroll
        for (int jj = 0; jj < HID; ++jj)
            acc = fmaf(Wc1[j*HID + jj], smem[H1OFF + jj * ELEMS + e], acc);
        smem[HIDOFF + j * ELEMS + e] = fmaxf(acc, 0.f);
    }
    __syncthreads();
    if (tid < 3 * ELEMS) {
        const int e = tid / 3, c = tid % 3;
        float vv = bc2[c];
        #pragma unroll
        for (int j = 0; j < HID; ++j)
            vv = fmaf(Wc2[c*HID + j], smem[HIDOFF + j * ELEMS + e], vv);
        out[(eA + e) * 3 + c] = vv;
    }
}

extern "C" void kernel_launch(void* const* d_in, const int* in_sizes, int n_in,
                              void* d_out, int out_size, void* d_ws, size_t ws_size,
                              hipStream_t stream) {
    const float* X    = (const float*)d_in[0];
    const float* Wih0 = (const float*)d_in[1];
    const float* Whh0 = (const float*)d_in[2];
    const float* bih0 = (const float*)d_in[3];
    const float* bhh0 = (const float*)d_in[4];
    const float* Wih1 = (const float*)d_in[5];
    const float* Whh1 = (const float*)d_in[6];
    const float* bih1 = (const float*)d_in[7];
    const float* bhh1 = (const float*)d_in[8];
    const float* Wc1  = (const float*)d_in[9];
    const float* bc1  = (const float*)d_in[10];
    const float* Wc2  = (const float*)d_in[11];
    const float* bc2  = (const float*)d_in[12];

    lstm_fused<<<1024, 512, 0, stream>>>(X, Wih0, Whh0, bih0, bhh0,
                                         Wih1, Whh1, bih1, bhh1,
                                         Wc1, bc1, Wc2, bc2, (float*)d_out);
}

// Round 6
// 1477.198 us; speedup vs baseline: 3.0167x; 1.0978x over previous
//
#include <hip/hip_runtime.h>

#define T_STEPS 1000
#define IN 13
#define HID 32
#define ELEMS 2
#define GRPSTEPS 4
#define GRPFLOATS (GRPSTEPS * IN * ELEMS)   // 104 floats per x-group
#define NGRP (T_STEPS / GRPSTEPS)           // 250
#define ZROWS 48                            // 32 h-rows + 13 x-rows + 3 zero pad
#define ZSLOT (ZROWS * ELEMS)               // 96 floats per slot
#define ZTOT  (8 * ZSLOT)                   // 768
#define H1OFF (ZTOT + 8)                    // h1 double buffer
#define HIDOFF (H1OFF + 2 * HID * ELEMS)    // 904
#define SMEMF  (HIDOFF + HID * ELEMS)       // 968 floats

typedef float v2f __attribute__((ext_vector_type(2)));

// ---- packed f32 FMA (CDNA4 dual-pipe): acc.{lo,hi} += z.{lo,hi} * w.bcast ----
// op_sel half-broadcast of src1: the SAME weight pair serves two rows (lo/hi half),
// so weights stay 1 VGPR per f32 (no duplication).
__device__ __forceinline__ void pk_fma_lo(v2f& acc, v2f z, v2f w) {   // w.lo both halves
    asm("v_pk_fma_f32 %0, %1, %2, %0 op_sel:[0,0,0] op_sel_hi:[1,0,1]"
        : "+v"(acc) : "v"(z), "v"(w));
}
__device__ __forceinline__ void pk_fma_hi(v2f& acc, v2f z, v2f w) {   // w.hi both halves
    asm("v_pk_fma_f32 %0, %1, %2, %0 op_sel:[0,1,0] op_sel_hi:[1,1,1]"
        : "+v"(acc) : "v"(z), "v"(w));
}

// ---- cross-lane primitives: DPP quad_perm (VALU pipe, no LDS) + ds_swizzle imm ----
#define DPP_XOR1 0xB1   // quad perm [1,0,3,2]
#define DPP_XOR2 0x4E   // quad perm [2,3,0,1]
#define DPP_XOR3 0x1B   // quad perm [3,2,1,0]
template<int CTRL>
__device__ __forceinline__ float dpp_qp(float x) {
    return __int_as_float(__builtin_amdgcn_update_dpp(
        0, __float_as_int(x), CTRL, 0xF, 0xF, true));
}
__device__ __forceinline__ float swz_xor4(float x) {   // xor lane^4 within 32 (imm pattern)
    return __int_as_float(__builtin_amdgcn_ds_swizzle(__float_as_int(x), 0x101F));
}

// Structure = R5 (8-lane K-chunk groups, exp2-domain activations, DPP reductions,
// asymmetric cell on lane q0==0), with the dual-elem dot core packed into
// v_pk_fma_f32: LDS stores (e0,e1) adjacent -> each row is one packed operand; one
// packed FMA per (gate,row) replaces two scalar FMAs. Bit-identical numerics to R5.
__global__ __launch_bounds__(512, 4)
void lstm_fused(const float* __restrict__ X,
                const float* __restrict__ Wih0, const float* __restrict__ Whh0,
                const float* __restrict__ bih0, const float* __restrict__ bhh0,
                const float* __restrict__ Wih1, const float* __restrict__ Whh1,
                const float* __restrict__ bih1, const float* __restrict__ bhh1,
                const float* __restrict__ Wc1,  const float* __restrict__ bc1,
                const float* __restrict__ Wc2,  const float* __restrict__ bc2,
                float* __restrict__ out)
{
    const int tid  = threadIdx.x;
    const bool isL1 = (tid >= 256);
    const int L    = tid & 255;             // layer-local thread
    const int u    = L >> 3;                // unit 0..31
    const int r    = L & 7;                 // K-chunk index
    const int q0   = r & 3;                 // gate owned after reduction
    const int e0f  = r >> 2;                // elem owned after reduction
    const int eA   = blockIdx.x * ELEMS;

    __shared__ __align__(16) float smem[SMEMF];

    const float SCL = -1.44269504088896340736f;         // -log2(e)
    const float sgate[4] = {SCL, SCL, 2.f * SCL, SCL};  // sigmoid: -log2e, tanh: -2log2e

    // ---- weights: 4 gates x chunk r, PRE-SCALED, stored as pairs (row 2i, row 2i+1)
    v2f wp[16];
    #pragma unroll
    for (int i = 0; i < 16; ++i) wp[i] = (v2f){0.f, 0.f};
    float bias;
    if (!isL1) {
        #pragma unroll
        for (int q = 0; q < 4; ++q) {
            const int row = (q << 5) | u;
            #pragma unroll
            for (int cc = 0; cc < 6; ++cc) {
                const int j = 6 * r + cc;               // [Whh | Wih | 0]
                float v;
                if (j < HID)          v = Whh0[row * HID + j];
                else if (j < HID+IN)  v = Wih0[row * IN + (j - HID)];
                else                  v = 0.f;
                wp[q * 3 + (cc >> 1)][cc & 1] = sgate[q] * v;
            }
        }
        const int rowf = (q0 << 5) | u;
        bias = sgate[q0] * (bih0[rowf] + bhh0[rowf]);
    } else {
        #pragma unroll
        for (int q = 0; q < 4; ++q) {
            const int row = (q << 5) | u;
            #pragma unroll
            for (int cc = 0; cc < 8; ++cc) {
                const int j = 8 * r + cc;               // [h0(32) | h1(32)]
                float v = (j < HID) ? Wih1[row * HID + j]
                                    : Whh1[row * HID + (j - HID)];
                wp[q * 4 + (cc >> 1)][cc & 1] = sgate[q] * v;
            }
        }
        const int rowf = (q0 << 5) | u;
        bias = sgate[q0] * (bih1[rowf] + bhh1[rowf]);
    }
    const float actA = (q0 == 2) ? 2.f : 1.f;
    const float actB = (q0 == 2) ? -1.f : 0.f;
    const float C2   = 2.f * SCL;                        // tanh(c) input scale

    // ---- zero zbuf (h-rows + pads) and h1[-1] ----
    for (int i = tid; i < ZTOT; i += 512) smem[i] = 0.f;
    if (tid < HID * ELEMS) smem[H1OFF + tid] = 0.f;     // h1 parity 0

    // ---- x staging: 52 stagers, float2 each, into x-rows (HID+i) of the slots ----
    const bool stager = (tid < GRPFLOATS / 2);          // tid < 52
    int off0 = 0, off1 = 0;
    const float* xg = nullptr;
    float2 xreg = make_float2(0.f, 0.f);
    if (stager) {
        int f0 = tid * 2, f1 = f0 + 1;
        int e0 = f0 / (GRPSTEPS * IN); int r0 = f0 % (GRPSTEPS * IN);
        int t0 = r0 / IN, i0 = r0 % IN;
        int r1 = f1 % (GRPSTEPS * IN);                  // f0 even, span 52 even -> same elem
        int t1 = r1 / IN, i1 = r1 % IN;
        off0 = t0 * ZSLOT + (HID + i0) * ELEMS + e0;
        off1 = t1 * ZSLOT + (HID + i1) * ELEMS + e0;
        xg = X + (size_t)(eA + e0) * (T_STEPS * IN) + (size_t)r0;
        float2 x0 = *(const float2*)xg;                 // group 0
        smem[off0] = x0.x;
        smem[off1] = x0.y;
        xreg = *(const float2*)(xg + GRPSTEPS * IN);    // prefetch group 1
    }
    __syncthreads();

    float cd = 0.f;     // f32 cell state; VALID ONLY on lanes with q0==0

    #pragma unroll 1
    for (int k = 0; k <= T_STEPS; ++k) {
        const int p   = k & 1;
        const int grp = k >> 2;
        const int ph  = k & 3;

        if (ph == 0 && stager) {
            if (grp + 1 < NGRP) {
                const int base = ((grp + 1) & 1) ? 4 * ZSLOT : 0;
                smem[base + off0] = xreg.x;
                smem[base + off1] = xreg.y;
            }
            if (grp + 2 < NGRP) xreg = *(const float2*)(xg + (size_t)(grp + 2) * GRPSTEPS * IN);
        }

        const bool active = isL1 ? (k >= 1) : (k < T_STEPS);
        if (active) {
            v2f ACC[4];                                  // ACC[q] = {e0, e1} partials
            #pragma unroll
            for (int q = 0; q < 4; ++q) ACC[q] = (v2f){0.f, 0.f};

            if (!isL1) {
                const float* zp = smem + (k & 7) * ZSLOT + r * 12;   // 6 rows x 2 elems
                float4 z0 = *(const float4*)(zp);
                float4 z1 = *(const float4*)(zp + 4);
                float4 z2 = *(const float4*)(zp + 8);
                v2f p0 = {z0.x, z0.y}, p1 = {z0.z, z0.w};
                v2f p2 = {z1.x, z1.y}, p3 = {z1.z, z1.w};
                v2f p4 = {z2.x, z2.y}, p5 = {z2.z, z2.w};
                #pragma unroll
                for (int q = 0; q < 4; ++q) {
                    pk_fma_lo(ACC[q], p0, wp[q*3+0]);
                    pk_fma_hi(ACC[q], p1, wp[q*3+0]);
                    pk_fma_lo(ACC[q], p2, wp[q*3+1]);
                    pk_fma_hi(ACC[q], p3, wp[q*3+1]);
                    pk_fma_lo(ACC[q], p4, wp[q*3+2]);
                    pk_fma_hi(ACC[q], p5, wp[q*3+2]);
                }
            } else {
                const float* zp = (r < 4)
                    ? (smem + (k & 7) * ZSLOT + r * 16)                       // h0_{k-1}
                    : (smem + H1OFF + ((p ^ 1) * HID * ELEMS) + (r - 4) * 16);// h1_{k-2}
                float4 z0 = *(const float4*)(zp);
                float4 z1 = *(const float4*)(zp + 4);
                float4 z2 = *(const float4*)(zp + 8);
                float4 z3 = *(const float4*)(zp + 12);
                v2f p0 = {z0.x, z0.y}, p1 = {z0.z, z0.w};
                v2f p2 = {z1.x, z1.y}, p3 = {z1.z, z1.w};
                v2f p4 = {z2.x, z2.y}, p5 = {z2.z, z2.w};
                v2f p6 = {z3.x, z3.y}, p7 = {z3.z, z3.w};
                #pragma unroll
                for (int q = 0; q < 4; ++q) {
                    pk_fma_lo(ACC[q], p0, wp[q*4+0]);
                    pk_fma_hi(ACC[q], p1, wp[q*4+0]);
                    pk_fma_lo(ACC[q], p2, wp[q*4+1]);
                    pk_fma_hi(ACC[q], p3, wp[q*4+1]);
                    pk_fma_lo(ACC[q], p4, wp[q*4+2]);
                    pk_fma_hi(ACC[q], p5, wp[q*4+2]);
                    pk_fma_lo(ACC[q], p6, wp[q*4+3]);
                    pk_fma_hi(ACC[q], p7, wp[q*4+3]);
                }
            }

            // ---- reduction over r: xor4 via ds_swizzle, xor2/xor1 via DPP quad_perm
            const bool hi4 = (r & 4), hi2 = (r & 2), hi1 = (r & 1);
            float S;
            {
                float s0 = hi4 ? ACC[0].x : ACC[0].y, k0 = hi4 ? ACC[0].y : ACC[0].x;
                float s1 = hi4 ? ACC[1].x : ACC[1].y, k1 = hi4 ? ACC[1].y : ACC[1].x;
                float s2 = hi4 ? ACC[2].x : ACC[2].y, k2 = hi4 ? ACC[2].y : ACC[2].x;
                float s3 = hi4 ? ACC[3].x : ACC[3].y, k3 = hi4 ? ACC[3].y : ACC[3].x;
                float B0 = k0 + swz_xor4(s0);
                float B1 = k1 + swz_xor4(s1);
                float B2 = k2 + swz_xor4(s2);
                float B3 = k3 + swz_xor4(s3);
                float s4 = hi2 ? B0 : B2, k4 = hi2 ? B2 : B0;
                float s5 = hi2 ? B1 : B3, k5 = hi2 ? B3 : B1;
                float C0 = k4 + dpp_qp<DPP_XOR2>(s4);
                float C1 = k5 + dpp_qp<DPP_XOR2>(s5);
                float s6 = hi1 ? C0 : C1, k6 = hi1 ? C1 : C0;
                S = k6 + dpp_qp<DPP_XOR1>(s6);
            }
            S += bias;

            // ---- activation in exp2 domain: v = fma(actA, rcp(1+exp2(S)), actB) ----
            float e2 = exp2f(S);
            float rr = __builtin_amdgcn_rcpf(1.0f + e2);
            float v  = fmaf(actA, rr, actB);    // lane q0: gate q0 of elem e0f

            // ---- asymmetric cell update (valid on lanes q0==0) ----
            float gg2  = dpp_qp<DPP_XOR2>(v);   // lane0 <- gg
            float prod = v * gg2;               // lane0: gi*gg
            float gf1  = dpp_qp<DPP_XOR1>(v);   // lane0 <- gf
            cd = fmaf(gf1, cd, prod);           // valid on q0==0 only
            float e2c = exp2f(cd * C2);
            float th  = fmaf(2.0f, __builtin_amdgcn_rcpf(1.0f + e2c), -1.0f); // tanh(c)
            float go3 = dpp_qp<DPP_XOR3>(v);    // lane0 <- go
            float hval = th * go3;

            if (q0 == 0) {                      // one writer per (unit, elem)
                if (!isL1) smem[((k + 1) & 7) * ZSLOT + u * ELEMS + e0f] = hval;
                else       smem[H1OFF + p * HID * ELEMS + u * ELEMS + e0f] = hval;
            }
        }
        __syncthreads();
    }

    // ---- classifier head (f32): hidden = relu(Wc1 @ h1 + bc1); out = Wc2 @ hidden + bc2
    // final h1 parity = (T_STEPS & 1) = 0
    if (tid < ELEMS * HID) {
        const int e = tid >> 5, j = tid & 31;
        float acc = bc1[j];
        #pragma unroll
        for (int jj = 0; jj < HID; ++jj)
            acc = fmaf(Wc1[j*HID + jj], smem[H1OFF + jj * ELEMS + e], acc);
        smem[HIDOFF + j * ELEMS + e] = fmaxf(acc, 0.f);
    }
    __syncthreads();
    if (tid < 3 * ELEMS) {
        const int e = tid / 3, c = tid % 3;
        float vv = bc2[c];
        #pragma unroll
        for (int j = 0; j < HID; ++j)
            vv = fmaf(Wc2[c*HID + j], smem[HIDOFF + j * ELEMS + e], vv);
        out[(eA + e) * 3 + c] = vv;
    }
}

extern "C" void kernel_launch(void* const* d_in, const int* in_sizes, int n_in,
                              void* d_out, int out_size, void* d_ws, size_t ws_size,
                              hipStream_t stream) {
    const float* X    = (const float*)d_in[0];
    const float* Wih0 = (const float*)d_in[1];
    const float* Whh0 = (const float*)d_in[2];
    const float* bih0 = (const float*)d_in[3];
    const float* bhh0 = (const float*)d_in[4];
    const float* Wih1 = (const float*)d_in[5];
    const float* Whh1 = (const float*)d_in[6];
    const float* bih1 = (const float*)d_in[7];
    const float* bhh1 = (const float*)d_in[8];
    const float* Wc1  = (const float*)d_in[9];
    const float* bc1  = (const float*)d_in[10];
    const float* Wc2  = (const float*)d_in[11];
    const float* bc2  = (const float*)d_in[12];

    lstm_fused<<<1024, 512, 0, stream>>>(X, Wih0, Whh0, bih0, bhh0,
                                         Wih1, Whh1, bih1, bhh1,
                                         Wc1, bc1, Wc2, bc2, (float*)d_out);
}